// Round 1
// baseline (52245.734 us; speedup 1.0000x reference)
//
#include <hip/hip_runtime.h>
#include <stdint.h>

#define HID 1024
#define G4  4096
#define BB  64

typedef short short8v __attribute__((ext_vector_type(8)));
typedef float float4v __attribute__((ext_vector_type(4)));

static __device__ __forceinline__ unsigned short f2bf(float f) {
    unsigned u = __builtin_bit_cast(unsigned, f);
    u += 0x7fffu + ((u >> 16) & 1u);
    return (unsigned short)(u >> 16);
}
static __device__ __forceinline__ float bf2f(unsigned short s) {
    unsigned u = ((unsigned)s) << 16;
    return __builtin_bit_cast(float, u);
}
static __device__ __forceinline__ float sigm(float x) { return 1.0f / (1.0f + __expf(-x)); }
static __device__ __forceinline__ float tanh_fast(float x) { return 2.0f / (1.0f + __expf(-2.0f * x)) - 1.0f; }

// ---------------- prep: bf16 converts + unit-major reorder + offsets ----------------
__global__ void prep_kernel(const float* __restrict__ data,
                            const int* __restrict__ bs_raw,
                            const float* __restrict__ Wih, const float* __restrict__ Whh,
                            const float* __restrict__ bih, const float* __restrict__ bhh,
                            const float* __restrict__ h0,
                            unsigned short* __restrict__ xb,
                            unsigned short* __restrict__ wih_r,
                            unsigned short* __restrict__ whh_r,
                            float* __restrict__ bias_r,
                            unsigned short* __restrict__ hb0, unsigned short* __restrict__ hb1,
                            int* __restrict__ bs_n, int* __restrict__ offs,
                            unsigned* __restrict__ bar,
                            int total, int T)
{
    int bid = blockIdx.x, tid = threadIdx.x;
    if (bid == 0) {
        __shared__ int sbs[1024];
        bool is64 = (T > 1) && (bs_raw[1] == 0);   // int64 batch_sizes => low word at 2*t
        for (int t = tid; t < T && t < 1024; t += 256) sbs[t] = is64 ? bs_raw[2 * t] : bs_raw[t];
        __syncthreads();
        if (tid == 0) {
            int acc = 0;
            for (int t = 0; t < T; ++t) { bs_n[t] = sbs[t]; offs[t] = acc; acc += sbs[t]; }
            bar[0] = 0u;
        }
        return;
    }
    long N0 = (long)total * (HID / 4);
    long N1 = N0 + (long)G4 * (HID / 4);
    long N2 = N1 + (long)G4 * (HID / 4);
    long N3 = N2 + G4;
    long N4 = N3 + BB * (HID / 4);
    long stride = (long)(gridDim.x - 1) * 256;
    for (long i = (long)(bid - 1) * 256 + tid; i < N4; i += stride) {
        if (i < N0) {
            float4 d = ((const float4*)data)[i];
            ((ushort4*)xb)[i] = make_ushort4(f2bf(d.x), f2bf(d.y), f2bf(d.z), f2bf(d.w));
        } else if (i < N1) {
            long j = i - N0; int r = (int)(j >> 8); int k4 = (int)(j & 255);
            int u = r >> 2, g = r & 3;
            float4 d = ((const float4*)Wih)[(long)(g * HID + u) * (HID / 4) + k4];
            ((ushort4*)wih_r)[j] = make_ushort4(f2bf(d.x), f2bf(d.y), f2bf(d.z), f2bf(d.w));
        } else if (i < N2) {
            long j = i - N1; int r = (int)(j >> 8); int k4 = (int)(j & 255);
            int u = r >> 2, g = r & 3;
            float4 d = ((const float4*)Whh)[(long)(g * HID + u) * (HID / 4) + k4];
            ((ushort4*)whh_r)[j] = make_ushort4(f2bf(d.x), f2bf(d.y), f2bf(d.z), f2bf(d.w));
        } else if (i < N3) {
            int r = (int)(i - N2); int u = r >> 2, g = r & 3;
            bias_r[r] = bih[g * HID + u] + bhh[g * HID + u];
        } else {
            long j = i - N3;
            float4 d = ((const float4*)h0)[j];
            ushort4 o = make_ushort4(f2bf(d.x), f2bf(d.y), f2bf(d.z), f2bf(d.w));
            ((ushort4*)hb0)[j] = o;
            ((ushort4*)hb1)[j] = o;
        }
    }
}

// ---------------- input GEMM: gI = xb @ wih_r^T  (bf16 out) ----------------
__global__ __launch_bounds__(256) void gemm_kernel(const unsigned short* __restrict__ xb,
                                                   const unsigned short* __restrict__ wr,
                                                   unsigned short* __restrict__ gI)
{
    __shared__ unsigned short As[128 * 32];
    __shared__ unsigned short Bs[128 * 32];
    int tid = threadIdx.x;
    int l = tid & 63;
    int w = tid >> 6;
    int m = l & 15, q = l >> 4;
    int mtile = blockIdx.x, ntile = blockIdx.y;

    const unsigned short* pa = xb + (long)(mtile * 128 + (tid >> 2)) * HID + (tid & 3) * 8;
    const unsigned short* pb = wr + (long)(ntile * 128 + (tid >> 2)) * HID + (tid & 3) * 8;
    unsigned short* la = As + (tid >> 2) * 32 + (tid & 3) * 8;
    unsigned short* lb = Bs + (tid >> 2) * 32 + (tid & 3) * 8;

    int RM = (w >> 1) * 64, CN = (w & 1) * 64;
    float4v acc[4][4];
#pragma unroll
    for (int i = 0; i < 4; ++i)
#pragma unroll
        for (int j = 0; j < 4; ++j) acc[i][j] = (float4v){0.f, 0.f, 0.f, 0.f};

    for (int kt = 0; kt < HID; kt += 32) {
        short8v a0 = *(const short8v*)(pa + kt);
        short8v a1 = *(const short8v*)(pa + 64 * HID + kt);
        short8v b0 = *(const short8v*)(pb + kt);
        short8v b1 = *(const short8v*)(pb + 64 * HID + kt);
        __syncthreads();
        *(short8v*)la = a0;
        *(short8v*)(la + 64 * 32) = a1;
        *(short8v*)lb = b0;
        *(short8v*)(lb + 64 * 32) = b1;
        __syncthreads();
        short8v av[4], bv[4];
#pragma unroll
        for (int i = 0; i < 4; ++i) av[i] = *(const short8v*)&As[(RM + i * 16 + m) * 32 + q * 8];
#pragma unroll
        for (int j = 0; j < 4; ++j) bv[j] = *(const short8v*)&Bs[(CN + j * 16 + m) * 32 + q * 8];
#pragma unroll
        for (int i = 0; i < 4; ++i)
#pragma unroll
            for (int j = 0; j < 4; ++j)
                acc[i][j] = __builtin_amdgcn_mfma_f32_16x16x32_bf16(av[i], bv[j], acc[i][j], 0, 0, 0);
    }
#pragma unroll
    for (int i = 0; i < 4; ++i)
#pragma unroll
        for (int j = 0; j < 4; ++j)
#pragma unroll
            for (int r = 0; r < 4; ++r) {
                int grow = mtile * 128 + RM + i * 16 + q * 4 + r;
                int gcol = ntile * 128 + CN + j * 16 + m;
                gI[(long)grow * G4 + gcol] = f2bf(acc[i][j][r]);
            }
}

// ---------------- persistent recurrent kernel ----------------
__global__ __launch_bounds__(256, 1) void lstm_kernel(
    const unsigned short* __restrict__ gI,
    const unsigned short* __restrict__ whh_r,
    const float* __restrict__ bias_r,
    unsigned short* __restrict__ hb0, unsigned short* __restrict__ hb1,
    const float* __restrict__ h0, const float* __restrict__ c0,
    const int* __restrict__ bs_n, const int* __restrict__ offs,
    unsigned* __restrict__ bar,
    float* __restrict__ out, float* __restrict__ hf, float* __restrict__ cf,
    int T)
{
    int tid = threadIdx.x, bid = blockIdx.x;
    int l = tid & 63;
    int w = tid >> 6;           // wave id == unit index u
    int m = l & 15, q = l >> 4;

    __shared__ int sbs[1024], soff[1024];
    __shared__ float sg[64 * 20];

    for (int i = tid; i < T && i < 1024; i += 256) { sbs[i] = bs_n[i]; soff[i] = offs[i]; }

    // W_hh B-fragments, register-resident: lane m is gate-column bid*16+m
    short8v Wf[32];
#pragma unroll
    for (int k = 0; k < 32; ++k)
        Wf[k] = *(const short8v*)&whh_r[(long)(bid * 16 + m) * HID + k * 32 + q * 8];

    int row = tid & 63;
    int u = tid >> 6;
    int col = bid * 4 + u;                 // global hidden unit
    float c_reg = c0[row * HID + col];
    float h_reg = h0[row * HID + col];
    float4 bia = *(const float4*)&bias_r[bid * 16 + u * 4];
    __syncthreads();

    for (int t = 0; t < T; ++t) {
        const unsigned short* hc = (t & 1) ? hb1 : hb0;
        unsigned short* hn = (t & 1) ? hb0 : hb1;
        int bs = sbs[t], off = soff[t];
        int bsn = (t + 1 < T) ? sbs[t + 1] : 0;

        // gates(h-part): wave w computes rows [16w,16w+16) x cols [16*bid,16*bid+16)
        short8v a[32];
#pragma unroll
        for (int k = 0; k < 32; ++k)
            a[k] = *(const short8v*)&hc[(w * 16 + m) * HID + k * 32 + q * 8];
        float4v acc = {0.f, 0.f, 0.f, 0.f};
#pragma unroll
        for (int k = 0; k < 32; ++k)
            acc = __builtin_amdgcn_mfma_f32_16x16x32_bf16(a[k], Wf[k], acc, 0, 0, 0);

#pragma unroll
        for (int r = 0; r < 4; ++r)
            sg[(w * 16 + q * 4 + r) * 20 + m] = acc[r];
        __syncthreads();

        float4 g = *(const float4*)&sg[row * 20 + u * 4];
        if (row < bs) {
            const unsigned short* gp = gI + (long)(off + row) * G4 + bid * 16 + u * 4;
            ushort4 gv = *(const ushort4*)gp;
            float gi = g.x + bia.x + bf2f(gv.x);
            float gf = g.y + bia.y + bf2f(gv.y);
            float gg = g.z + bia.z + bf2f(gv.z);
            float go = g.w + bia.w + bf2f(gv.w);
            float fi = sigm(gi), ff = sigm(gf), fg = tanh_fast(gg), fo = sigm(go);
            c_reg = ff * c_reg + fi * fg;
            float hv = fo * tanh_fast(c_reg);
            h_reg = hv;
            out[(size_t)(off + row) * HID + col] = hv;
            if (t + 1 >= T || row >= bsn) {
                hf[row * HID + col] = hv;
                cf[row * HID + col] = c_reg;
            }
        }
        hn[row * HID + col] = f2bf(h_reg);   // frozen rows re-publish old value

        if (t + 1 < T) {
            __builtin_amdgcn_fence(__ATOMIC_RELEASE, "agent");   // drain + wbL2
            __syncthreads();
            if (tid == 0) {
                __hip_atomic_fetch_add(bar, 1u, __ATOMIC_RELAXED, __HIP_MEMORY_SCOPE_AGENT);
                unsigned tgt = (unsigned)(t + 1) * 256u;
                while (__hip_atomic_load(bar, __ATOMIC_RELAXED, __HIP_MEMORY_SCOPE_AGENT) < tgt)
                    __builtin_amdgcn_s_sleep(2);
            }
            __syncthreads();
            __builtin_amdgcn_fence(__ATOMIC_ACQUIRE, "agent");   // inv L1/L2-stale
        }
    }
}

extern "C" void kernel_launch(void* const* d_in, const int* in_sizes, int n_in,
                              void* d_out, int out_size, void* d_ws, size_t ws_size,
                              hipStream_t stream)
{
    const float* data = (const float*)d_in[0];
    const int* bs_raw = (const int*)d_in[1];
    const float* Wih = (const float*)d_in[2];
    const float* Whh = (const float*)d_in[3];
    const float* bih = (const float*)d_in[4];
    const float* bhh = (const float*)d_in[5];
    const float* h0 = (const float*)d_in[6];
    const float* c0 = (const float*)d_in[7];
    int total = in_sizes[0] / HID;     // 47872
    int T = in_sizes[1];               // 1000

    char* p = (char*)d_ws;
    unsigned short* gI = (unsigned short*)p;     p += (size_t)total * G4 * 2;
    unsigned short* xb = (unsigned short*)p;     p += (size_t)total * HID * 2;
    unsigned short* wih_r = (unsigned short*)p;  p += (size_t)G4 * HID * 2;
    unsigned short* whh_r = (unsigned short*)p;  p += (size_t)G4 * HID * 2;
    float* bias_r = (float*)p;                   p += (size_t)G4 * 4;
    unsigned short* hbuf0 = (unsigned short*)p;  p += (size_t)BB * HID * 2;
    unsigned short* hbuf1 = (unsigned short*)p;  p += (size_t)BB * HID * 2;
    int* bs_n = (int*)p;                         p += 4096;
    int* offs = (int*)p;                         p += 4096;
    unsigned* bar = (unsigned*)p;                p += 256;

    float* out = (float*)d_out;
    float* hf = out + (size_t)total * HID;
    float* cf = hf + (size_t)BB * HID;

    prep_kernel<<<4097, 256, 0, stream>>>(data, bs_raw, Wih, Whh, bih, bhh, h0,
                                          xb, wih_r, whh_r, bias_r, hbuf0, hbuf1,
                                          bs_n, offs, bar, total, T);
    gemm_kernel<<<dim3(total / 128, G4 / 128), 256, 0, stream>>>(xb, wih_r, gI);
    lstm_kernel<<<256, 256, 0, stream>>>(gI, whh_r, bias_r, hbuf0, hbuf1, h0, c0,
                                         bs_n, offs, bar, out, hf, cf, T);
}

// Round 2
// 14456.583 us; speedup vs baseline: 3.6140x; 3.6140x over previous
//
#include <hip/hip_runtime.h>
#include <stdint.h>

#define HID 1024
#define G4  4096
#define BB  64

typedef short short8v __attribute__((ext_vector_type(8)));
typedef float float4v __attribute__((ext_vector_type(4)));
typedef unsigned long long ull;

static __device__ __forceinline__ unsigned short f2bf(float f) {
    unsigned u = __builtin_bit_cast(unsigned, f);
    u += 0x7fffu + ((u >> 16) & 1u);
    return (unsigned short)(u >> 16);
}
static __device__ __forceinline__ float bf2f(unsigned short s) {
    unsigned u = ((unsigned)s) << 16;
    return __builtin_bit_cast(float, u);
}
static __device__ __forceinline__ float sigm(float x) { return 1.0f / (1.0f + __expf(-x)); }
static __device__ __forceinline__ float tanh_fast(float x) { return 2.0f / (1.0f + __expf(-2.0f * x)) - 1.0f; }

// ---------------- prep: bf16 converts + unit-major reorder + offsets ----------------
__global__ void prep_kernel(const float* __restrict__ data,
                            const int* __restrict__ bs_raw,
                            const float* __restrict__ Wih, const float* __restrict__ Whh,
                            const float* __restrict__ bih, const float* __restrict__ bhh,
                            const float* __restrict__ h0,
                            unsigned short* __restrict__ xb,
                            unsigned short* __restrict__ wih_r,
                            unsigned short* __restrict__ whh_r,
                            float* __restrict__ bias_r,
                            unsigned short* __restrict__ hb0, unsigned short* __restrict__ hb1,
                            int* __restrict__ bs_n, int* __restrict__ offs,
                            unsigned* __restrict__ bar,
                            int total, int T)
{
    int bid = blockIdx.x, tid = threadIdx.x;
    if (bid == 0) {
        __shared__ int sbs[1024];
        bool is64 = (T > 1) && (bs_raw[1] == 0);   // int64 batch_sizes => low word at 2*t
        for (int t = tid; t < T && t < 1024; t += 256) sbs[t] = is64 ? bs_raw[2 * t] : bs_raw[t];
        __syncthreads();
        if (tid == 0) {
            int acc = 0;
            for (int t = 0; t < T; ++t) { bs_n[t] = sbs[t]; offs[t] = acc; acc += sbs[t]; }
            bar[0] = 0u;
        }
        return;
    }
    long N0 = (long)total * (HID / 4);
    long N1 = N0 + (long)G4 * (HID / 4);
    long N2 = N1 + (long)G4 * (HID / 4);
    long N3 = N2 + G4;
    long N4 = N3 + BB * (HID / 4);
    long stride = (long)(gridDim.x - 1) * 256;
    for (long i = (long)(bid - 1) * 256 + tid; i < N4; i += stride) {
        if (i < N0) {
            float4 d = ((const float4*)data)[i];
            ((ushort4*)xb)[i] = make_ushort4(f2bf(d.x), f2bf(d.y), f2bf(d.z), f2bf(d.w));
        } else if (i < N1) {
            long j = i - N0; int r = (int)(j >> 8); int k4 = (int)(j & 255);
            int u = r >> 2, g = r & 3;
            float4 d = ((const float4*)Wih)[(long)(g * HID + u) * (HID / 4) + k4];
            ((ushort4*)wih_r)[j] = make_ushort4(f2bf(d.x), f2bf(d.y), f2bf(d.z), f2bf(d.w));
        } else if (i < N2) {
            long j = i - N1; int r = (int)(j >> 8); int k4 = (int)(j & 255);
            int u = r >> 2, g = r & 3;
            float4 d = ((const float4*)Whh)[(long)(g * HID + u) * (HID / 4) + k4];
            ((ushort4*)whh_r)[j] = make_ushort4(f2bf(d.x), f2bf(d.y), f2bf(d.z), f2bf(d.w));
        } else if (i < N3) {
            int r = (int)(i - N2); int u = r >> 2, g = r & 3;
            bias_r[r] = bih[g * HID + u] + bhh[g * HID + u];
        } else {
            long j = i - N3;
            float4 d = ((const float4*)h0)[j];
            ushort4 o = make_ushort4(f2bf(d.x), f2bf(d.y), f2bf(d.z), f2bf(d.w));
            ((ushort4*)hb0)[j] = o;
            ((ushort4*)hb1)[j] = o;
        }
    }
}

// ---------------- input GEMM: gI = xb @ wih_r^T  (bf16 out) ----------------
__global__ __launch_bounds__(256) void gemm_kernel(const unsigned short* __restrict__ xb,
                                                   const unsigned short* __restrict__ wr,
                                                   unsigned short* __restrict__ gI)
{
    __shared__ unsigned short As[128 * 32];
    __shared__ unsigned short Bs[128 * 32];
    int tid = threadIdx.x;
    int l = tid & 63;
    int w = tid >> 6;
    int m = l & 15, q = l >> 4;
    int mtile = blockIdx.x, ntile = blockIdx.y;

    const unsigned short* pa = xb + (long)(mtile * 128 + (tid >> 2)) * HID + (tid & 3) * 8;
    const unsigned short* pb = wr + (long)(ntile * 128 + (tid >> 2)) * HID + (tid & 3) * 8;
    unsigned short* la = As + (tid >> 2) * 32 + (tid & 3) * 8;
    unsigned short* lb = Bs + (tid >> 2) * 32 + (tid & 3) * 8;

    int RM = (w >> 1) * 64, CN = (w & 1) * 64;
    float4v acc[4][4];
#pragma unroll
    for (int i = 0; i < 4; ++i)
#pragma unroll
        for (int j = 0; j < 4; ++j) acc[i][j] = (float4v){0.f, 0.f, 0.f, 0.f};

    for (int kt = 0; kt < HID; kt += 32) {
        short8v a0 = *(const short8v*)(pa + kt);
        short8v a1 = *(const short8v*)(pa + 64 * HID + kt);
        short8v b0 = *(const short8v*)(pb + kt);
        short8v b1 = *(const short8v*)(pb + 64 * HID + kt);
        __syncthreads();
        *(short8v*)la = a0;
        *(short8v*)(la + 64 * 32) = a1;
        *(short8v*)lb = b0;
        *(short8v*)(lb + 64 * 32) = b1;
        __syncthreads();
        short8v av[4], bv[4];
#pragma unroll
        for (int i = 0; i < 4; ++i) av[i] = *(const short8v*)&As[(RM + i * 16 + m) * 32 + q * 8];
#pragma unroll
        for (int j = 0; j < 4; ++j) bv[j] = *(const short8v*)&Bs[(CN + j * 16 + m) * 32 + q * 8];
#pragma unroll
        for (int i = 0; i < 4; ++i)
#pragma unroll
            for (int j = 0; j < 4; ++j)
                acc[i][j] = __builtin_amdgcn_mfma_f32_16x16x32_bf16(av[i], bv[j], acc[i][j], 0, 0, 0);
    }
#pragma unroll
    for (int i = 0; i < 4; ++i)
#pragma unroll
        for (int j = 0; j < 4; ++j)
#pragma unroll
            for (int r = 0; r < 4; ++r) {
                int grow = mtile * 128 + RM + i * 16 + q * 4 + r;
                int gcol = ntile * 128 + CN + j * 16 + m;
                gI[(long)grow * G4 + gcol] = f2bf(acc[i][j][r]);
            }
}

// ---------------- persistent recurrent kernel ----------------
// 64 blocks x 1024 threads. Block bid owns hidden units [bid*16, bid*16+16)
// = gate cols [bid*64, bid*64+64). 16 waves = 4 row-groups x 4 col-groups.
// No cache-wide fences: all cross-block traffic uses per-access AGENT-scope
// atomics (routed to the IC coherence point); everything else stays cached.
__global__ __launch_bounds__(1024) void lstm_kernel(
    const unsigned short* __restrict__ gI,
    const unsigned short* __restrict__ whh_r,
    const float* __restrict__ bias_r,
    unsigned short* __restrict__ hb0, unsigned short* __restrict__ hb1,
    const float* __restrict__ h0, const float* __restrict__ c0,
    const int* __restrict__ bs_n, const int* __restrict__ offs,
    unsigned* __restrict__ bar,
    float* __restrict__ out, float* __restrict__ hf, float* __restrict__ cf,
    int T)
{
    __shared__ unsigned short hlds[64 * 1032];   // h staged, row pad +8 shorts (2-way free)
    __shared__ float sg[64 * 68];                // gate transpose tile
    __shared__ int sbs[1024], soff[1024];

    int tid = threadIdx.x, bid = blockIdx.x;
    int lane = tid & 63;
    int w = tid >> 6;            // wave 0..15
    int m = lane & 15, q = lane >> 4;
    int rg = w & 3, cg = w >> 2; // row-group, col-group

    for (int i = tid; i < T && i < 1024; i += 1024) { sbs[i] = bs_n[i]; soff[i] = offs[i]; }

    // activation-phase thread mapping
    int u = tid & 15;            // unit within block
    int row = tid >> 4;          // batch row 0..63
    int col = bid * 16 + u;      // global hidden unit
    float c_reg = c0[row * HID + col];
    float h_reg = h0[row * HID + col];
    float4 bia = *(const float4*)&bias_r[bid * 64 + 4 * u];

    // W_hh fragment base (re-read each step; block's 131KB slice stays L2-resident)
    const unsigned short* wp = whh_r + (size_t)(bid * 64 + cg * 16 + m) * HID + q * 8;
    const unsigned short* ap = hlds + (rg * 16 + m) * 1032 + q * 8;

    __syncthreads();

    for (int t = 0; t < T; ++t) {
        const ull* hq = (const ull*)((t & 1) ? hb1 : hb0);
        unsigned* hn = (unsigned*)((t & 1) ? hb0 : hb1);
        int bs = sbs[t], off = soff[t];
        int bsn = (t + 1 < T) ? sbs[t + 1] : 0;

        // gI prefetch (no h dependency) — in flight under the h staging loads
        ushort4 gv = make_ushort4(0, 0, 0, 0);
        if (row < bs)
            gv = *(const ushort4*)(gI + (size_t)(off + row) * G4 + bid * 64 + 4 * u);

        // stage h (131KB) into LDS via agent-coherent qword loads
        ull st[16];
#pragma unroll
        for (int it = 0; it < 8; ++it) {
            st[2 * it]     = __hip_atomic_load(hq + 2 * tid + (size_t)it * 2048,
                                               __ATOMIC_RELAXED, __HIP_MEMORY_SCOPE_AGENT);
            st[2 * it + 1] = __hip_atomic_load(hq + 2 * tid + (size_t)it * 2048 + 1,
                                               __ATOMIC_RELAXED, __HIP_MEMORY_SCOPE_AGENT);
        }
        {
            unsigned short* lb = hlds + (tid >> 7) * 1032 + (tid & 127) * 8;
#pragma unroll
            for (int it = 0; it < 8; ++it) {
                *(ull*)(lb + (size_t)it * 8256)     = st[2 * it];
                *(ull*)(lb + (size_t)it * 8256 + 4) = st[2 * it + 1];
            }
        }
        __syncthreads();   // [A] hlds ready (also drains gI load)

        // gates(h-part): wave (rg,cg) -> rows [16rg,+16) x cols [bid*64+16cg,+16)
        float4v acc = {0.f, 0.f, 0.f, 0.f};
#pragma unroll
        for (int k = 0; k < 32; ++k) {
            short8v a  = *(const short8v*)(ap + k * 32);
            short8v wf = *(const short8v*)(wp + k * 32);
            acc = __builtin_amdgcn_mfma_f32_16x16x32_bf16(a, wf, acc, 0, 0, 0);
        }
#pragma unroll
        for (int r = 0; r < 4; ++r)
            sg[(rg * 16 + q * 4 + r) * 68 + cg * 16 + m] = acc[r];
        __syncthreads();   // [B] sg ready

        // activation: thread = (row, unit)
        float4 g = *(const float4*)&sg[row * 68 + 4 * u];
        if (row < bs) {
            float gi = g.x + bia.x + bf2f(gv.x);
            float gf = g.y + bia.y + bf2f(gv.y);
            float gg = g.z + bia.z + bf2f(gv.z);
            float go = g.w + bia.w + bf2f(gv.w);
            float fi = sigm(gi), ff = sigm(gf), fg = tanh_fast(gg), fo = sigm(go);
            c_reg = ff * c_reg + fi * fg;
            float hv = fo * tanh_fast(c_reg);
            h_reg = hv;
            out[(size_t)(off + row) * HID + col] = hv;
            if (t + 1 >= T || row >= bsn) {
                hf[row * HID + col] = hv;
                cf[row * HID + col] = c_reg;
            }
        }
        // publish h: pack 2 cols -> uint, agent-scope store (write-through to IC)
        {
            float hp = __shfl_xor(h_reg, 1);
            if ((u & 1) == 0) {
                unsigned pk = (unsigned)f2bf(h_reg) | ((unsigned)f2bf(hp) << 16);
                __hip_atomic_store(hn + row * (HID / 2) + bid * 8 + (u >> 1), pk,
                                   __ATOMIC_RELAXED, __HIP_MEMORY_SCOPE_AGENT);
            }
        }

        if (t + 1 < T) {
            asm volatile("s_waitcnt vmcnt(0)" ::: "memory");
            __syncthreads();   // [C] all waves' stores drained (s_barrier implies vmcnt(0))
            if (tid == 0) {
                __hip_atomic_fetch_add(bar, 1u, __ATOMIC_RELAXED, __HIP_MEMORY_SCOPE_AGENT);
                unsigned tgt = (unsigned)(t + 1) * 64u;
                while (__hip_atomic_load(bar, __ATOMIC_RELAXED, __HIP_MEMORY_SCOPE_AGENT) < tgt)
                    __builtin_amdgcn_s_sleep(1);
            }
            __syncthreads();   // [D] released
        }
    }
}

extern "C" void kernel_launch(void* const* d_in, const int* in_sizes, int n_in,
                              void* d_out, int out_size, void* d_ws, size_t ws_size,
                              hipStream_t stream)
{
    const float* data = (const float*)d_in[0];
    const int* bs_raw = (const int*)d_in[1];
    const float* Wih = (const float*)d_in[2];
    const float* Whh = (const float*)d_in[3];
    const float* bih = (const float*)d_in[4];
    const float* bhh = (const float*)d_in[5];
    const float* h0 = (const float*)d_in[6];
    const float* c0 = (const float*)d_in[7];
    int total = in_sizes[0] / HID;     // 47872
    int T = in_sizes[1];               // 1000

    char* p = (char*)d_ws;
    unsigned short* gI = (unsigned short*)p;     p += (size_t)total * G4 * 2;
    unsigned short* xb = (unsigned short*)p;     p += (size_t)total * HID * 2;
    unsigned short* wih_r = (unsigned short*)p;  p += (size_t)G4 * HID * 2;
    unsigned short* whh_r = (unsigned short*)p;  p += (size_t)G4 * HID * 2;
    float* bias_r = (float*)p;                   p += (size_t)G4 * 4;
    unsigned short* hbuf0 = (unsigned short*)p;  p += (size_t)BB * HID * 2;
    unsigned short* hbuf1 = (unsigned short*)p;  p += (size_t)BB * HID * 2;
    int* bs_n = (int*)p;                         p += 4096;
    int* offs = (int*)p;                         p += 4096;
    unsigned* bar = (unsigned*)p;                p += 256;

    float* out = (float*)d_out;
    float* hf = out + (size_t)total * HID;
    float* cf = hf + (size_t)BB * HID;

    prep_kernel<<<4097, 256, 0, stream>>>(data, bs_raw, Wih, Whh, bih, bhh, h0,
                                          xb, wih_r, whh_r, bias_r, hbuf0, hbuf1,
                                          bs_n, offs, bar, total, T);
    gemm_kernel<<<dim3(total / 128, G4 / 128), 256, 0, stream>>>(xb, wih_r, gI);
    lstm_kernel<<<64, 1024, 0, stream>>>(gI, whh_r, bias_r, hbuf0, hbuf1, h0, c0,
                                         bs_n, offs, bar, out, hf, cf, T);
}